// Round 1
// 1754.542 us; speedup vs baseline: 1.1831x; 1.1831x over previous
//
#include <hip/hip_runtime.h>
#include <hip/hip_fp16.h>

// Sinkhorn / entropic Wasserstein, N=M=8192, D=32, EPS=10, <=50 iters.
// R2: Ks = 2^8 * exp(-C/EPS) stored fp8 e4m3 (64 MB), fused row+col sweeps,
//     8-row sub-band L2-hot re-read. 2076 us.
// R3: loop is latency-bound, not byte-bound (80 MB/iter => 12.7 us floor, Ks is
//     L3-resident, measured ~39 us/iter). Kill the bubbles:
//     (1) register double-buffer prefetch: next sub's row loads + this sub's col
//         loads issued BEFORE the reduce/barrier section (sched_barrier pinned);
//     (2) 8 -> 4 barriers/iter: redundant all-thread a-compute, rowhalf double-
//         buffered by sub parity, arow LDS removed;
//     (3) O(1) convergence check (1 load/thread + block reduce) instead of
//         256 serial loads per thread.

#define NN 8192
#define DDIM 32
#define EPSF 10.0f
#define LOG2E 1.44269504088896340736f
#define LN2F 0.69314718055994530942f
#define KLOG2 8.0f           // Ks = 2^8 * K  (max 256 < 448 e4m3 max)
#define THRESH2 1e-10f       // (1e-5)^2

// ---- workspace layout (bytes) ----
#define OFF_KS   0ull                        // 8192*8192 fp8 = 67108864
#define OFF_PART (67108864ull)               // 256*8192 fp32 = 8388608
#define OFF_A    (OFF_PART + 8388608ull)     // 8192 fp32
#define OFF_B    (OFF_A + 32768ull)          // 8192 fp32
#define OFF_X2   (OFF_B + 32768ull)          // 8192 fp32
#define OFF_Y2   (OFF_X2 + 32768ull)         // 8192 fp32
#define OFF_ERR  (OFF_Y2 + 32768ull)         // 256 fp32 err partials
#define WS_NEEDED (OFF_ERR + 4096ull)        // ~75.6 MB

typedef float floatx2 __attribute__((ext_vector_type(2)));

#if __has_builtin(__builtin_amdgcn_cvt_pk_f32_fp8) && __has_builtin(__builtin_amdgcn_cvt_pk_fp8_f32)
#define HW_FP8 1
#else
#define HW_FP8 0
#include <hip/hip_fp8.h>
#endif

__device__ __forceinline__ void fp8x4_to_f32(unsigned int w, float* f) {
#if HW_FP8
    floatx2 lo = __builtin_amdgcn_cvt_pk_f32_fp8((int)w, false);
    floatx2 hi = __builtin_amdgcn_cvt_pk_f32_fp8((int)w, true);
    f[0] = lo.x; f[1] = lo.y; f[2] = hi.x; f[3] = hi.y;
#else
    for (int i = 0; i < 4; ++i) {
        __hip_fp8_e4m3 h; h.__x = (__hip_fp8_storage_t)((w >> (8 * i)) & 0xff);
        f[i] = (float)h;
    }
#endif
}

__device__ __forceinline__ unsigned char f32_to_fp8(float v) {
#if HW_FP8
    return (unsigned char)(__builtin_amdgcn_cvt_pk_fp8_f32(v, v, 0, false) & 0xff);
#else
    __hip_fp8_e4m3 h(v);
    return (unsigned char)h.__x;
#endif
}

// ---- init: x2, y2 row norms; b=1; errpart=big; out[0]=0 ----
__global__ __launch_bounds__(256) void k_init(const float* __restrict__ x,
                                              const float* __restrict__ y,
                                              float* __restrict__ x2,
                                              float* __restrict__ y2,
                                              float* __restrict__ b,
                                              float* __restrict__ errpart,
                                              float* __restrict__ out) {
    int t = blockIdx.x * 256 + threadIdx.x;   // grid 32 -> t in [0,8192)
    const float4* x4 = (const float4*)(x + (size_t)t * DDIM);
    float s = 0.f;
#pragma unroll
    for (int k = 0; k < 8; ++k) { float4 v = x4[k]; s += v.x*v.x + v.y*v.y + v.z*v.z + v.w*v.w; }
    x2[t] = s;
    const float4* y4 = (const float4*)(y + (size_t)t * DDIM);
    s = 0.f;
#pragma unroll
    for (int k = 0; k < 8; ++k) { float4 v = y4[k]; s += v.x*v.x + v.y*v.y + v.z*v.z + v.w*v.w; }
    y2[t] = s;
    b[t] = 1.0f;
    if (t < 256) errpart[t] = 1e30f;
    if (t == 0) out[0] = 0.f;
}

// ---- build Ks (fp8): tile 32 rows x 256 cols per WG, grid 8192 ----
__global__ __launch_bounds__(256) void k_build(const float* __restrict__ x,
                                               const float* __restrict__ y,
                                               const float* __restrict__ x2,
                                               const float* __restrict__ y2,
                                               unsigned char* __restrict__ Ks) {
    __shared__ float yT[DDIM][256];               // [d][col] 32 KB
    __shared__ float xT[DDIM][32];                // [d][row]  4 KB
    __shared__ __align__(16) unsigned char hb8[32][256]; // bounce 8 KB
    const int t = threadIdx.x;
    const int jb = blockIdx.x & 31;               // 32 col blocks of 256
    const int ib = blockIdx.x >> 5;               // 256 row blocks of 32
    const int colbase = jb * 256, rowbase = ib * 32;

    {
        const float4* yp = (const float4*)(y + (size_t)(colbase + t) * DDIM);
#pragma unroll
        for (int k = 0; k < 8; ++k) {
            float4 v = yp[k];
            yT[4*k+0][t] = v.x; yT[4*k+1][t] = v.y; yT[4*k+2][t] = v.z; yT[4*k+3][t] = v.w;
        }
    }
    {
        int r = t >> 3, ds = (t & 7) * 4;
        float4 v = *(const float4*)(x + (size_t)(rowbase + r) * DDIM + ds);
        xT[ds+0][r] = v.x; xT[ds+1][r] = v.y; xT[ds+2][r] = v.z; xT[ds+3][r] = v.w;
    }
    __syncthreads();

    float acc[32];
#pragma unroll
    for (int r = 0; r < 32; ++r) acc[r] = 0.f;
    for (int d = 0; d < DDIM; ++d) {
        float yv = yT[d][t];
#pragma unroll
        for (int r4 = 0; r4 < 8; ++r4) {
            float4 xv = *(const float4*)&xT[d][r4 * 4];
            acc[r4*4+0] = fmaf(xv.x, yv, acc[r4*4+0]);
            acc[r4*4+1] = fmaf(xv.y, yv, acc[r4*4+1]);
            acc[r4*4+2] = fmaf(xv.z, yv, acc[r4*4+2]);
            acc[r4*4+3] = fmaf(xv.w, yv, acc[r4*4+3]);
        }
    }
    const float y2c = y2[colbase + t];
#pragma unroll
    for (int r = 0; r < 32; ++r) {
        float Cv = fmaxf(x2[rowbase + r] + y2c - 2.f * acc[r], 0.f);
        float arg = KLOG2 - Cv * (LOG2E / EPSF);
        hb8[r][t] = f32_to_fp8(__builtin_amdgcn_exp2f(arg));
    }
    __syncthreads();
    // coalesced store: 32 rows x 256B via LDS bounce; thread u -> 32 B
    {
        int row = t >> 3, off = (t & 7) * 32;
        uint4 v0 = *(const uint4*)&hb8[row][off];
        uint4 v1 = *(const uint4*)&hb8[row][off + 16];
        unsigned char* dst = Ks + (size_t)(rowbase + row) * NN + colbase + off;
        *(uint4*)dst = v0;
        *(uint4*)(dst + 16) = v1;
    }
}

// row-pass consume: one uint4 (16 fp8) against swizzled b in LDS
#define ROWFMA(KV, KC) { \
    const unsigned int* kw_ = (const unsigned int*)&(KV); \
    _Pragma("unroll") \
    for (int j4 = 0; j4 < 4; ++j4) { \
        float kf_[4]; \
        fp8x4_to_f32(kw_[j4], kf_); \
        float4 bv_ = b4[((KC) * 4 + j4) * 64 + lane]; \
        rs = fmaf(kf_[0], bv_.x, rs); \
        rs = fmaf(kf_[1], bv_.y, rs); \
        rs = fmaf(kf_[2], bv_.z, rs); \
        rs = fmaf(kf_[3], bv_.w, rs); \
    } }

// col-pass consume: one uint2 (8 fp8) scaled by a-value into 8 col accumulators
#define COLFMA(KV, AV) { \
    float kf_[8]; \
    fp8x4_to_f32((KV).x, kf_); \
    fp8x4_to_f32((KV).y, kf_ + 4); \
    _Pragma("unroll") \
    for (int j = 0; j < 8; ++j) cacc[j] = fmaf(kf_[j], (AV), cacc[j]); }

// ---- fused iteration: per WG a 32-row band; row pass then L2-hot col pass ----
// R3: register double-buffered row prefetch + early col-load issue so Ks loads
// stay in flight across the reduce/barrier sections; 1 barrier per sub.
__global__ __launch_bounds__(1024) void k_iter(const unsigned char* __restrict__ Ks,
                                               const float* __restrict__ bg,
                                               const float* __restrict__ p,
                                               float* __restrict__ a_out,
                                               float* __restrict__ part,
                                               const float* __restrict__ errpart) {
    __shared__ float bsw[NN];          // 32 KB swizzled b
    __shared__ float rowhalf[2][8][2]; // double-buffered by sub parity
    __shared__ float dred[17];
    const int t = threadIdx.x;
    const int w = t >> 6, lane = t & 63;
    const int band = blockIdx.x * 32;
    const int rl = w >> 1, half = w & 1;

    // issue everything with latency up front: b-stage, err value, sub-0 rows
    float4 g0 = ((const float4*)bg)[2 * t];
    float4 g1 = ((const float4*)bg)[2 * t + 1];
    float e = (t < 256) ? errpart[t] : 0.f;
    const uint4* kp0 = (const uint4*)(Ks + (size_t)(band + rl) * NN + half * 4096);
    uint4 ka0 = kp0[lane], ka1 = kp0[64 + lane], ka2 = kp0[128 + lane], ka3 = kp0[192 + lane];
    __builtin_amdgcn_sched_barrier(0);

    // O(1) convergence check (deterministic block reduce of 256 partials)
#pragma unroll
    for (int off = 32; off > 0; off >>= 1) e += __shfl_down(e, off, 64);
    if (lane == 0) dred[w] = e;
    __syncthreads();
    if (t == 0) dred[16] = (dred[0] + dred[1]) + (dred[2] + dred[3]);
    __syncthreads();
    if (dred[16] < THRESH2) return;    // frozen: no further updates

    // stage b into swizzled LDS: float col c at
    // [ (c>>10)*1024 + ((c>>2)&3)*256 + ((c>>4)&63)*4 + (c&3) ]
    {
        float vals[8] = {g0.x, g0.y, g0.z, g0.w, g1.x, g1.y, g1.z, g1.w};
        int c0 = t * 8;
#pragma unroll
        for (int u = 0; u < 8; ++u) {
            int c = c0 + u;
            bsw[(c >> 10) * 1024 + ((c >> 2) & 3) * 256 + ((c >> 4) & 63) * 4 + (c & 3)] = vals[u];
        }
    }
    __syncthreads();

    float cacc[8] = {0.f, 0.f, 0.f, 0.f, 0.f, 0.f, 0.f, 0.f};
    const float4* b4 = (const float4*)bsw;

#pragma unroll
    for (int sub = 0; sub < 4; ++sub) {
        const int sb = sub & 1;
        // early-issue: this sub's col loads (L2-hot, older in vmcnt FIFO) then
        // next sub's row loads (HBM/L3, newest). Consuming cv never waits on kb.
        const uint2* kp2 = (const uint2*)(Ks + (size_t)(band + sub * 8) * NN);
        uint2 cv0 = kp2[0 * (NN / 8) + t], cv1 = kp2[1 * (NN / 8) + t],
              cv2 = kp2[2 * (NN / 8) + t], cv3 = kp2[3 * (NN / 8) + t],
              cv4 = kp2[4 * (NN / 8) + t], cv5 = kp2[5 * (NN / 8) + t],
              cv6 = kp2[6 * (NN / 8) + t], cv7 = kp2[7 * (NN / 8) + t];
        uint4 kb0 = {0,0,0,0}, kb1 = {0,0,0,0}, kb2 = {0,0,0,0}, kb3 = {0,0,0,0};
        if (sub < 3) {
            const uint4* kp = (const uint4*)(Ks + (size_t)(band + (sub + 1) * 8 + rl) * NN + half * 4096);
            kb0 = kp[lane]; kb1 = kp[64 + lane]; kb2 = kp[128 + lane]; kb3 = kp[192 + lane];
        }
        __builtin_amdgcn_sched_barrier(0);  // pin the prefetch issue point

        // ---- row pass: wave w owns row rl, half `half` (4096 cols) ----
        float rs = 0.f;
        ROWFMA(ka0, half * 4 + 0)
        ROWFMA(ka1, half * 4 + 1)
        ROWFMA(ka2, half * 4 + 2)
        ROWFMA(ka3, half * 4 + 3)
#pragma unroll
        for (int off = 32; off > 0; off >>= 1) rs += __shfl_down(rs, off, 64);
        if (lane == 0) rowhalf[sb][rl][half] = rs;
        __syncthreads();

        // ---- all threads compute the 8 a-values redundantly (no 2nd barrier;
        //      rowhalf parity-buffered so next sub's writes can't race) ----
        const int rg = band + sub * 8;
        float av0 = p[rg + 0] / (rowhalf[sb][0][0] + rowhalf[sb][0][1]);
        float av1 = p[rg + 1] / (rowhalf[sb][1][0] + rowhalf[sb][1][1]);
        float av2 = p[rg + 2] / (rowhalf[sb][2][0] + rowhalf[sb][2][1]);
        float av3 = p[rg + 3] / (rowhalf[sb][3][0] + rowhalf[sb][3][1]);
        float av4 = p[rg + 4] / (rowhalf[sb][4][0] + rowhalf[sb][4][1]);
        float av5 = p[rg + 5] / (rowhalf[sb][5][0] + rowhalf[sb][5][1]);
        float av6 = p[rg + 6] / (rowhalf[sb][6][0] + rowhalf[sb][6][1]);
        float av7 = p[rg + 7] / (rowhalf[sb][7][0] + rowhalf[sb][7][1]);
        if (t == 0) {
            *(float4*)(a_out + rg)     = make_float4(av0, av1, av2, av3);
            *(float4*)(a_out + rg + 4) = make_float4(av4, av5, av6, av7);
        }

        // ---- col pass: thread t owns cols [8t, 8t+8); data already in flight ----
        COLFMA(cv0, av0)
        COLFMA(cv1, av1)
        COLFMA(cv2, av2)
        COLFMA(cv3, av3)
        COLFMA(cv4, av4)
        COLFMA(cv5, av5)
        COLFMA(cv6, av6)
        COLFMA(cv7, av7)

        if (sub < 3) { ka0 = kb0; ka1 = kb1; ka2 = kb2; ka3 = kb3; }
    }
    float4* pp = (float4*)(part + (size_t)blockIdx.x * NN + t * 8);
    pp[0] = make_float4(cacc[0], cacc[1], cacc[2], cacc[3]);
    pp[1] = make_float4(cacc[4], cacc[5], cacc[6], cacc[7]);
}

// ---- finalize b: sum 256 partials per col; deterministic err partials ----
__global__ __launch_bounds__(256) void k_div(const float* __restrict__ part,
                                             const float* __restrict__ q,
                                             float* __restrict__ b,
                                             float* __restrict__ errpart) {
    const int t = threadIdx.x;
    __shared__ float red[8][32];
    __shared__ float esc[32];
    __shared__ float dsum[5];
    {   // O(1) done check (keep frozen state intact)
        float e = errpart[t];
#pragma unroll
        for (int off = 32; off > 0; off >>= 1) e += __shfl_down(e, off, 64);
        if ((t & 63) == 0) dsum[t >> 6] = e;
        __syncthreads();
        if (t == 0) dsum[4] = (dsum[0] + dsum[1]) + (dsum[2] + dsum[3]);
        __syncthreads();
        if (dsum[4] < THRESH2) return;
    }
    const int c = t & 31, ibc = t >> 5;      // grid 256: 32 cols/WG, 8 chunk-rows
    const int col = blockIdx.x * 32 + c;
    float s = 0.f;
#pragma unroll 4
    for (int i = 0; i < 32; ++i) s += part[(size_t)(ibc * 32 + i) * NN + col];
    red[ibc][c] = s;
    __syncthreads();
    if (ibc == 0) {
        float sum = 0.f;
#pragma unroll
        for (int k = 0; k < 8; ++k) sum += red[k][c];
        float bn = q[col] / sum;
        float d = bn - b[col];
        b[col] = bn;
        esc[c] = d * d;
    }
    __syncthreads();
    if (t == 0) {
        float e = 0.f;
#pragma unroll
        for (int k = 0; k < 32; ++k) e += esc[k];
        errpart[blockIdx.x] = e;
    }
}

// ---- final: T = a*Ks*b (scale-invariant), w = sum T*C, C from log2(Ks) ----
__global__ __launch_bounds__(256) void k_final(const unsigned char* __restrict__ Ks,
                                               const float* __restrict__ a,
                                               const float* __restrict__ b,
                                               float* __restrict__ out) {
    const int t = threadIdx.x;
    const int row = blockIdx.x;              // grid 8192
    const float ai = a[row];
    const uint2* kp = (const uint2*)(Ks + (size_t)row * NN);
    float* Trow = out + 1 + (size_t)row * NN;
    float w = 0.f;
    const float c1 = EPSF * LN2F;
#pragma unroll
    for (int k = 0; k < 4; ++k) {
        const int col = k * 2048 + t * 8;
        uint2 kv = kp[k * 256 + t];
        float kf[8];
        fp8x4_to_f32(kv.x, kf);
        fp8x4_to_f32(kv.y, kf + 4);
        float4 b0 = *(const float4*)(b + col);
        float4 b1 = *(const float4*)(b + col + 4);
        float bv[8] = {b0.x, b0.y, b0.z, b0.w, b1.x, b1.y, b1.z, b1.w};
#pragma unroll
        for (int j = 0; j < 8; ++j) {
            float ks = kf[j];
            float Tv = ai * ks * bv[j];
            float Cv = c1 * (KLOG2 - __builtin_amdgcn_logf(fmaxf(ks, 1e-35f)));
            w = fmaf(Tv, Cv, w);
            Trow[col + j] = Tv;              // d_out+1: scalar stores (offset 4B)
        }
    }
#pragma unroll
    for (int off = 32; off > 0; off >>= 1) w += __shfl_down(w, off, 64);
    __shared__ float red[4];
    if ((t & 63) == 0) red[t >> 6] = w;
    __syncthreads();
    if (t == 0) atomicAdd(out, (red[0] + red[1]) + (red[2] + red[3]));
}

extern "C" void kernel_launch(void* const* d_in, const int* in_sizes, int n_in,
                              void* d_out, int out_size, void* d_ws, size_t ws_size,
                              hipStream_t stream) {
    const float* x = (const float*)d_in[0];
    const float* y = (const float*)d_in[1];
    const float* p = (const float*)d_in[2];
    const float* q = (const float*)d_in[3];
    float* out = (float*)d_out;
    if (ws_size < WS_NEEDED) return;
    char* ws = (char*)d_ws;
    unsigned char* Ks = (unsigned char*)(ws + OFF_KS);
    float* part = (float*)(ws + OFF_PART);
    float* a = (float*)(ws + OFF_A);
    float* b = (float*)(ws + OFF_B);
    float* x2 = (float*)(ws + OFF_X2);
    float* y2 = (float*)(ws + OFF_Y2);
    float* errpart = (float*)(ws + OFF_ERR);

    k_init<<<dim3(32), dim3(256), 0, stream>>>(x, y, x2, y2, b, errpart, out);
    k_build<<<dim3(8192), dim3(256), 0, stream>>>(x, y, x2, y2, Ks);
    for (int it = 0; it < 50; ++it) {
        k_iter<<<dim3(256), dim3(1024), 0, stream>>>(Ks, b, p, a, part, errpart);
        k_div<<<dim3(256), dim3(256), 0, stream>>>(part, q, b, errpart);
    }
    k_final<<<dim3(8192), dim3(256), 0, stream>>>(Ks, a, b, out);
}